// Round 17
// baseline (93.716 us; speedup 1.0000x reference)
//
#include <hip/hip_runtime.h>
#include <hip/hip_fp16.h>

// B=4, T=4096, C=1024, H=64 single attention head, causal, NO 1/sqrt(d) scale.
// wsplit: W -> hi/lo bf16 frag-stream. proj_mfma: 3-term split-bf16 MFMA GEMM ->
// qh/ql/kh/kl (hi/lo bf16) + vt (bf16 [B][64][T]); 64 rows x 64 cols per block
// (3 col-blocks per row-tile, XCD-colocated so sibling x reads are L2 hits),
// grid 768 -> 2 resident blocks/CU + 3 pipelined rounds. W reg-dbuf, x prefetch.
// attn_part_block: 128 q-rows/block, K/V double-buffered LDS (2-phase pipeline),
// swapped QK^T, V-hoist, defer-max. PT=4 parts. combine: one wave per output row.

typedef __attribute__((ext_vector_type(8))) short bf16x8;
typedef __attribute__((ext_vector_type(8))) unsigned short u16x8;
typedef __attribute__((ext_vector_type(4))) float f32x4;

__device__ __forceinline__ unsigned short f2bf(float f) {
  unsigned u = __float_as_uint(f);
  u += 0x7fffu + ((u >> 16) & 1u);   // RTNE (finite values only here)
  return (unsigned short)(u >> 16);
}
__device__ __forceinline__ float bf2f(unsigned short s) {
  return __uint_as_float(((unsigned)s) << 16);
}
__device__ __forceinline__ unsigned cvt_pk_bf16(float lo, float hi) {
  unsigned r;
  asm("v_cvt_pk_bf16_f32 %0, %1, %2" : "=v"(r) : "v"(lo), "v"(hi));
  return r;
}
__device__ __forceinline__ void gload_lds16(const void* g, void* l) {
  __builtin_amdgcn_global_load_lds(
      (const __attribute__((address_space(1))) unsigned int*)g,
      (__attribute__((address_space(3))) unsigned int*)l, 16, 0, 0);
}
// XOR swizzle within a [64][128B] LDS tile: spreads column-strided b128 reads
#define KSWZ(row, colb) ((((row) * 128) + (colb)) ^ (((row) & 7) << 4))

// ---------------- W split: frag-stream layout ----------------
__global__ __launch_bounds__(256) void wsplit_kernel(
    const float* __restrict__ Wq, const float* __restrict__ Wk,
    const float* __restrict__ Wv,
    unsigned short* __restrict__ Wth, unsigned short* __restrict__ Wtl) {
  const int fl = blockIdx.x * 256 + threadIdx.x;   // [0, 24576)
  const int lane = fl & 63;
  const int rest = fl >> 6;        // [0, 384)
  const int nf = rest % 12;
  const int ksq = rest / 12;       // [0, 32)
  const int n = nf * 16 + (lane & 15);
  const int k0 = ksq * 32 + (lane >> 4) * 8;
  const float* wp = (n < 64) ? Wq : ((n < 128) ? Wk : Wv);
  const int h = n & 63;
  u16x8 hi, lo;
#pragma unroll
  for (int j = 0; j < 8; ++j) {
    float v = wp[(size_t)(k0 + j) * 64 + h];
    unsigned short hh = f2bf(v);
    hi[j] = hh;
    lo[j] = f2bf(v - bf2f(hh));
  }
  const size_t base = (size_t)fl * 8;
  *reinterpret_cast<u16x8*>(&Wth[base]) = hi;
  *reinterpret_cast<u16x8*>(&Wtl[base]) = lo;
}

// convert 8 f32 (two float4) -> hi/lo bf16x8 and store to LDS (16B each)
__device__ __forceinline__ void cvt_store8(unsigned short* dh, unsigned short* dl,
                                           const float4& a, const float4& b) {
  float v[8] = {a.x, a.y, a.z, a.w, b.x, b.y, b.z, b.w};
  uint4 hp, lp;
  unsigned* hpp = reinterpret_cast<unsigned*>(&hp);
  unsigned* lpp = reinterpret_cast<unsigned*>(&lp);
#pragma unroll
  for (int p = 0; p < 4; ++p) {
    const unsigned h = cvt_pk_bf16(v[2 * p], v[2 * p + 1]);
    hpp[p] = h;
    const float h0 = __uint_as_float(h << 16);
    const float h1 = __uint_as_float(h & 0xffff0000u);
    lpp[p] = cvt_pk_bf16(v[2 * p] - h0, v[2 * p + 1] - h1);
  }
  *reinterpret_cast<uint4*>(dh) = hp;
  *reinterpret_cast<uint4*>(dl) = lp;
}

// ---------------- projection via MFMA: [16384 x 1024] * [1024 x 192] ----------------
// 768 blocks: (row-tile of 64 rows) x (col-block of 64 cols = 4 nfrags).
// XCD decode: xcd=bx&7, kk=bx>>3, rowtile=xcd*32+kk/3, colb=kk%3 -> the 3 col
// siblings of a row-tile run consecutively on one XCD (x reads L2-shared).
// 4 waves; wave w owns nfrag nf = colb*4+w (16 cols), 4 mfrags. W reg-dbuf,
// x 2-step reg prefetch, LDS A-tile double-buffered.
__global__ __launch_bounds__(256) void proj_mfma_kernel(
    const float* __restrict__ x,
    const unsigned short* __restrict__ Wth, const unsigned short* __restrict__ Wtl,
    unsigned short* __restrict__ qh, unsigned short* __restrict__ ql,
    unsigned short* __restrict__ kh, unsigned short* __restrict__ kl,
    unsigned short* __restrict__ vt) {
  __shared__ unsigned short Ah[2][64][72];
  __shared__ unsigned short Al[2][64][72];
  const int tid = threadIdx.x;
  const int w = tid >> 6;
  const int lane = tid & 63;
  const int l16 = lane & 15;
  const int g = lane >> 4;
  const int bx = blockIdx.x;
  const int xcd = bx & 7;
  const int kk = bx >> 3;                 // [0, 96)
  const int row0 = (xcd * 32 + kk / 3) * 64;
  const int nf = (kk % 3) * 4 + w;        // wave's nfrag [0,12), wave-uniform
  const int sr = tid >> 2;                // staging row 0..63
  const int sc = (tid & 3) * 16;          // staging col 0,16,32,48

  f32x4 acc[4];
#pragma unroll
  for (int m = 0; m < 4; ++m) {
    f32x4 z = {0.f, 0.f, 0.f, 0.f};
    acc[m] = z;
  }

  const float* xp = &x[(size_t)(row0 + sr) * 1024 + sc];

  // x register sets: set0 = even slices, set1 = odd slices (4 float4 = 16 floats)
  float4 xs0[4], xs1[4];
#pragma unroll
  for (int i = 0; i < 4; ++i) xs0[i] = *reinterpret_cast<const float4*>(xp + i * 4);
#pragma unroll
  for (int i = 0; i < 4; ++i) xs1[i] = *reinterpret_cast<const float4*>(xp + 64 + i * 4);
  cvt_store8(&Ah[0][sr][sc], &Al[0][sr][sc], xs0[0], xs0[1]);       // slice 0 -> buf 0
  cvt_store8(&Ah[0][sr][sc + 8], &Al[0][sr][sc + 8], xs0[2], xs0[3]);

  // W current registers (step 0): 2 K-slices x 1 nfrag
  bf16x8 bhc[2], blc[2];
#pragma unroll
  for (int ks = 0; ks < 2; ++ks) {
    const size_t off = ((size_t)ks * 12 + nf) * 512 + lane * 8;
    bhc[ks] = *reinterpret_cast<const bf16x8*>(&Wth[off]);
    blc[ks] = *reinterpret_cast<const bf16x8*>(&Wtl[off]);
  }

#pragma unroll 2
  for (int step = 0; step < 16; ++step) {
    __syncthreads();
    // prefetch W for step+1
    bf16x8 bhn[2], bln[2];
    if (step < 15) {
#pragma unroll
      for (int ks = 0; ks < 2; ++ks) {
        const size_t off = ((size_t)((step + 1) * 2 + ks) * 12 + nf) * 512 + lane * 8;
        bhn[ks] = *reinterpret_cast<const bf16x8*>(&Wth[off]);
        bln[ks] = *reinterpret_cast<const bf16x8*>(&Wtl[off]);
      }
    }
    // issue x loads for slice step+2 into set[step&1]
    if (step < 14) {
      const float* px = xp + (size_t)(step + 2) * 64;
      if ((step & 1) == 0) {
#pragma unroll
        for (int i = 0; i < 4; ++i) xs0[i] = *reinterpret_cast<const float4*>(px + i * 4);
      } else {
#pragma unroll
        for (int i = 0; i < 4; ++i) xs1[i] = *reinterpret_cast<const float4*>(px + i * 4);
      }
    }
    // MFMAs on buf[step&1] with current W regs
    const int cur = step & 1;
#pragma unroll
    for (int ks = 0; ks < 2; ++ks) {
      bf16x8 ah[4], al[4];
#pragma unroll
      for (int m = 0; m < 4; ++m) {
        const int ro = m * 16 + l16;
        const int co = ks * 32 + g * 8;
        ah[m] = *reinterpret_cast<const bf16x8*>(&Ah[cur][ro][co]);
        al[m] = *reinterpret_cast<const bf16x8*>(&Al[cur][ro][co]);
      }
#pragma unroll
      for (int m = 0; m < 4; ++m) {
        acc[m] = __builtin_amdgcn_mfma_f32_16x16x32_bf16(ah[m], bhc[ks], acc[m], 0, 0, 0);
        acc[m] = __builtin_amdgcn_mfma_f32_16x16x32_bf16(ah[m], blc[ks], acc[m], 0, 0, 0);
        acc[m] = __builtin_amdgcn_mfma_f32_16x16x32_bf16(al[m], bhc[ks], acc[m], 0, 0, 0);
      }
    }
    // convert slice step+1 (loaded >= 1 full step ago) -> buf[cur^1]
    if (step < 15) {
      if (((step + 1) & 1) == 0) {
        cvt_store8(&Ah[cur ^ 1][sr][sc], &Al[cur ^ 1][sr][sc], xs0[0], xs0[1]);
        cvt_store8(&Ah[cur ^ 1][sr][sc + 8], &Al[cur ^ 1][sr][sc + 8], xs0[2], xs0[3]);
      } else {
        cvt_store8(&Ah[cur ^ 1][sr][sc], &Al[cur ^ 1][sr][sc], xs1[0], xs1[1]);
        cvt_store8(&Ah[cur ^ 1][sr][sc + 8], &Al[cur ^ 1][sr][sc + 8], xs1[2], xs1[3]);
      }
    }
    // rotate W registers
#pragma unroll
    for (int ks = 0; ks < 2; ++ks) {
      bhc[ks] = bhn[ks];
      blc[ks] = bln[ks];
    }
  }

  // epilogue: this wave's single nfrag (wave-uniform branch)
  const int b = row0 >> 12;
  const int tbase = row0 & 4095;
  const int nn = nf * 16;
  if (nn < 64) {
    const int h = nn + l16;
#pragma unroll
    for (int m = 0; m < 4; ++m)
#pragma unroll
      for (int j = 0; j < 4; ++j) {
        const int row = row0 + m * 16 + 4 * g + j;
        const float val = acc[m][j];
        const unsigned short hi = f2bf(val);
        qh[(size_t)row * 64 + h] = hi;
        ql[(size_t)row * 64 + h] = f2bf(val - bf2f(hi));
      }
  } else if (nn < 128) {
    const int h = nn - 64 + l16;
#pragma unroll
    for (int m = 0; m < 4; ++m)
#pragma unroll
      for (int j = 0; j < 4; ++j) {
        const int row = row0 + m * 16 + 4 * g + j;
        const float val = acc[m][j];
        const unsigned short hi = f2bf(val);
        kh[(size_t)row * 64 + h] = hi;
        kl[(size_t)row * 64 + h] = f2bf(val - bf2f(hi));
      }
  } else {
    const int h = nn - 128 + l16;
#pragma unroll
    for (int m = 0; m < 4; ++m) {
      ushort4 pv;
      pv.x = f2bf(acc[m][0]);
      pv.y = f2bf(acc[m][1]);
      pv.z = f2bf(acc[m][2]);
      pv.w = f2bf(acc[m][3]);
      const size_t a = ((size_t)b * 64 + h) * 4096 + tbase + m * 16 + 4 * g;
      *reinterpret_cast<ushort4*>(&vt[a]) = pv;
    }
  }
}

// ---------------- attention partials: 128-row block, double-buffered LDS K/V ----------------
// 2-phase pipeline: top-of-loop barrier drains buf[cur]; stage(t+1 -> cur^1)
// issued immediately after, in flight during compute(t).
template <int PT, int NU_B>
__global__ __launch_bounds__(256) void attn_part_block_kernel(
    const unsigned short* __restrict__ qh, const unsigned short* __restrict__ ql,
    const unsigned short* __restrict__ kh, const unsigned short* __restrict__ kl,
    const unsigned short* __restrict__ vt,
    __half* __restrict__ OP, float* __restrict__ ML) {
  __shared__ __align__(16) unsigned short Khs[2][4096];  // [64][64] bf16, XOR-swizzled
  __shared__ __align__(16) unsigned short Kls[2][4096];
  __shared__ __align__(16) unsigned short Vs[2][4096];   // rows = h, cols = kv
  __shared__ __align__(16) unsigned short pbuf[4][2][16][88];
  const int tid = threadIdx.x;
  const int w = tid >> 6;
  const int lane = tid & 63;
  const int l16 = lane & 15;
  const int g = lane >> 4;

  const int bx = blockIdx.x;
  const int xc = bx & 7;
  const int b = xc >> 1;                       // batch -> 2 XCDs
  const int s = 2 * (bx >> 3) + (xc & 1);      // [0, NU_B)
  int k = 0, pref = 0;
  for (;;) {
    const int np = (2 * k + 2 + PT - 1) / PT;
    if (s < pref + np) break;
    pref += np;
    ++k;
  }
  const int j4 = k;
  const int p = s - pref;
  const int ntiles = 2 * j4 + 2;
  const int t0 = p * PT;
  const int t1 = min(ntiles, t0 + PT);
  const int q0 = j4 * 128 + w * 32;            // wave's q base
  const size_t rowbase = (size_t)b * 4096;

  // staging indices (per thread, loop-invariant)
  const int te0 = w * 64 + lane;               // half 0 chunk
  const int te1 = 256 + w * 64 + lane;         // half 1 chunk
  const int r0_ = te0 >> 3, c80 = (te0 & 7) ^ (r0_ & 7);
  const int r1_ = te1 >> 3, c81 = (te1 & 7) ^ (r1_ & 7);
  const int lo0 = te0 * 16, lo1 = te1 * 16;    // linear LDS byte offsets

  bf16x8 q0hf[2], q0lf[2], q1hf[2], q1lf[2];
#pragma unroll
  for (int ss = 0; ss < 2; ++ss) {
    size_t a0 = (rowbase + q0 + l16) * 64 + ss * 32 + g * 8;
    q0hf[ss] = *reinterpret_cast<const bf16x8*>(&qh[a0]);
    q0lf[ss] = *reinterpret_cast<const bf16x8*>(&ql[a0]);
    size_t a1 = a0 + 16 * 64;
    q1hf[ss] = *reinterpret_cast<const bf16x8*>(&qh[a1]);
    q1lf[ss] = *reinterpret_cast<const bf16x8*>(&ql[a1]);
  }

  f32x4 o0[4], o1[4];
#pragma unroll
  for (int hb = 0; hb < 4; ++hb) {
    f32x4 z = {0.f, 0.f, 0.f, 0.f};
    o0[hb] = z;
    o1[hb] = z;
  }
  float m0 = -1e30f, l0 = 0.f, m1 = -1e30f, l1 = 0.f;

  // prologue: stage tile t0 into buf 0
  {
    const int kv0 = t0 * 64;
    gload_lds16(&kh[(rowbase + kv0 + r0_) * 64 + c80 * 8], (char*)Khs[0] + lo0);
    gload_lds16(&kl[(rowbase + kv0 + r0_) * 64 + c80 * 8], (char*)Kls[0] + lo0);
    gload_lds16(&vt[((size_t)b * 64 + r0_) * 4096 + kv0 + c80 * 8], (char*)Vs[0] + lo0);
    gload_lds16(&kh[(rowbase + kv0 + r1_) * 64 + c81 * 8], (char*)Khs[0] + lo1);
    gload_lds16(&kl[(rowbase + kv0 + r1_) * 64 + c81 * 8], (char*)Kls[0] + lo1);
    gload_lds16(&vt[((size_t)b * 64 + r1_) * 4096 + kv0 + c81 * 8], (char*)Vs[0] + lo1);
  }

  int cur = 0;
  for (int t = t0; t < t1; ++t) {
    __syncthreads();   // drains vmcnt: buf[cur] ready for all waves
    // prefetch next tile into buf[cur^1] (in flight during compute)
    if (t + 1 < t1) {
      const int kn = (t + 1) * 64;
      gload_lds16(&kh[(rowbase + kn + r0_) * 64 + c80 * 8], (char*)Khs[cur ^ 1] + lo0);
      gload_lds16(&kl[(rowbase + kn + r0_) * 64 + c80 * 8], (char*)Kls[cur ^ 1] + lo0);
      gload_lds16(&vt[((size_t)b * 64 + r0_) * 4096 + kn + c80 * 8], (char*)Vs[cur ^ 1] + lo0);
      gload_lds16(&kh[(rowbase + kn + r1_) * 64 + c81 * 8], (char*)Khs[cur ^ 1] + lo1);
      gload_lds16(&kl[(rowbase + kn + r1_) * 64 + c81 * 8], (char*)Kls[cur ^ 1] + lo1);
      gload_lds16(&vt[((size_t)b * 64 + r1_) * 4096 + kn + c81 * 8], (char*)Vs[cur ^ 1] + lo1);
    }
    const int kv0 = t * 64;

    f32x4 s0[4], s1[4];
#pragma unroll
    for (int kb = 0; kb < 4; ++kb) {
      bf16x8 khf[2], klf[2];
#pragma unroll
      for (int ss = 0; ss < 2; ++ss) {
        const int row = kb * 16 + l16;
        const int colb = ss * 64 + g * 16;
        khf[ss] = *reinterpret_cast<const bf16x8*>((const char*)Khs[cur] + KSWZ(row, colb));
        klf[ss] = *reinterpret_cast<const bf16x8*>((const char*)Kls[cur] + KSWZ(row, colb));
      }
      f32x4 a0 = {0.f, 0.f, 0.f, 0.f};
      f32x4 a1 = {0.f, 0.f, 0.f, 0.f};
#pragma unroll
      for (int ss = 0; ss < 2; ++ss) {
        a0 = __builtin_amdgcn_mfma_f32_16x16x32_bf16(khf[ss], q0hf[ss], a0, 0, 0, 0);
        a0 = __builtin_amdgcn_mfma_f32_16x16x32_bf16(khf[ss], q0lf[ss], a0, 0, 0, 0);
        a0 = __builtin_amdgcn_mfma_f32_16x16x32_bf16(klf[ss], q0hf[ss], a0, 0, 0, 0);
        a1 = __builtin_amdgcn_mfma_f32_16x16x32_bf16(khf[ss], q1hf[ss], a1, 0, 0, 0);
        a1 = __builtin_amdgcn_mfma_f32_16x16x32_bf16(khf[ss], q1lf[ss], a1, 0, 0, 0);
        a1 = __builtin_amdgcn_mfma_f32_16x16x32_bf16(klf[ss], q1hf[ss], a1, 0, 0, 0);
      }
      s0[kb] = a0;
      s1[kb] = a1;
    }
    // V fragments from LDS, issued EARLY (complete under softmax)
    bf16x8 vf[2][4];
#pragma unroll
    for (int ks = 0; ks < 2; ++ks)
#pragma unroll
      for (int hb = 0; hb < 4; ++hb) {
        const int row = hb * 16 + l16;
        const int colb = ks * 64 + g * 16;
        vf[ks][hb] = *reinterpret_cast<const bf16x8*>((const char*)Vs[cur] + KSWZ(row, colb));
      }
    if (kv0 + 63 > q0) {
#pragma unroll
      for (int kb = 0; kb < 4; ++kb)
#pragma unroll
        for (int jj = 0; jj < 4; ++jj) {
          const int kvg = kv0 + kb * 16 + 4 * g + jj;
          if (kvg > q0 + l16) s0[kb][jj] = -1e30f;
          if (kvg > q0 + 16 + l16) s1[kb][jj] = -1e30f;
        }
    }
    float rm0 = s0[0][0], rm1 = s1[0][0];
#pragma unroll
    for (int kb = 0; kb < 4; ++kb) {
      float c0 = fmaxf(fmaxf(s0[kb][0], s0[kb][1]), fmaxf(s0[kb][2], s0[kb][3]));
      float c1 = fmaxf(fmaxf(s1[kb][0], s1[kb][1]), fmaxf(s1[kb][2], s1[kb][3]));
      rm0 = fmaxf(rm0, c0);
      rm1 = fmaxf(rm1, c1);
    }
    rm0 = fmaxf(rm0, __shfl_xor(rm0, 16));
    rm0 = fmaxf(rm0, __shfl_xor(rm0, 32));
    rm1 = fmaxf(rm1, __shfl_xor(rm1, 16));
    rm1 = fmaxf(rm1, __shfl_xor(rm1, 32));
    const bool r0 = !__all(rm0 - m0 <= 8.f);   // wave-uniform
    const bool r1 = !__all(rm1 - m1 <= 8.f);
    const float mu0 = r0 ? fmaxf(m0, rm0) : m0;
    const float mu1 = r1 ? fmaxf(m1, rm1) : m1;
    const float al0 = r0 ? __expf(m0 - mu0) : 1.f;
    const float al1 = r1 ? __expf(m1 - mu1) : 1.f;
    float ps0 = 0.f, ps1 = 0.f;
#pragma unroll
    for (int kb = 0; kb < 4; ++kb)
#pragma unroll
      for (int jj = 0; jj < 4; ++jj) {
        const float e0 = __expf(s0[kb][jj] - mu0);
        const float e1 = __expf(s1[kb][jj] - mu1);
        s0[kb][jj] = e0;
        s1[kb][jj] = e1;
        ps0 += e0;
        ps1 += e1;
      }
    ps0 += __shfl_xor(ps0, 16);
    ps0 += __shfl_xor(ps0, 32);
    ps1 += __shfl_xor(ps1, 16);
    ps1 += __shfl_xor(ps1, 32);
    l0 = l0 * al0 + ps0;
    m0 = mu0;
    l1 = l1 * al1 + ps1;
    m1 = mu1;
#pragma unroll
    for (int kb = 0; kb < 4; ++kb) {
      *reinterpret_cast<unsigned*>(&pbuf[w][0][l16][kb * 16 + 4 * g]) =
          cvt_pk_bf16(s0[kb][0], s0[kb][1]);
      *reinterpret_cast<unsigned*>(&pbuf[w][0][l16][kb * 16 + 4 * g + 2]) =
          cvt_pk_bf16(s0[kb][2], s0[kb][3]);
      *reinterpret_cast<unsigned*>(&pbuf[w][1][l16][kb * 16 + 4 * g]) =
          cvt_pk_bf16(s1[kb][0], s1[kb][1]);
      *reinterpret_cast<unsigned*>(&pbuf[w][1][l16][kb * 16 + 4 * g + 2]) =
          cvt_pk_bf16(s1[kb][2], s1[kb][3]);
    }
    if (r0) {
#pragma unroll
      for (int jj = 0; jj < 4; ++jj) {
        const float a0r = __shfl(al0, 4 * g + jj);
#pragma unroll
        for (int hb = 0; hb < 4; ++hb) o0[hb][jj] *= a0r;
      }
    }
    if (r1) {
#pragma unroll
      for (int jj = 0; jj < 4; ++jj) {
        const float a1r = __shfl(al1, 4 * g + jj);
#pragma unroll
        for (int hb = 0; hb < 4; ++hb) o1[hb][jj] *= a1r;
      }
    }
    asm volatile("s_waitcnt lgkmcnt(0)" ::: "memory");
#pragma unroll
    for (int ks = 0; ks < 2; ++ks) {
      bf16x8 pa0 = *reinterpret_cast<const bf16x8*>(&pbuf[w][0][l16][ks * 32 + g * 8]);
      bf16x8 pa1 = *reinterpret_cast<const bf16x8*>(&pbuf[w][1][l16][ks * 32 + g * 8]);
#pragma unroll
      for (int hb = 0; hb < 4; ++hb) {
        o0[hb] = __builtin_amdgcn_mfma_f32_16x16x32_bf16(pa0, vf[ks][hb], o0[hb], 0, 0, 0);
        o1[hb] = __builtin_amdgcn_mfma_f32_16x16x32_bf16(pa1, vf[ks][hb], o1[hb], 0, 0, 0);
      }
    }
    cur ^= 1;
  }

  const size_t u = (size_t)b * NU_B + s;
  __half* op = OP + u * 8192 + (size_t)w * 32 * 64;   // [128][64] per unit
#pragma unroll
  for (int jj = 0; jj < 4; ++jj) {
    const int srcr = 4 * g + jj;
    const float l0r = __shfl(l0, srcr);
    const float l1r = __shfl(l1, srcr);
#pragma unroll
    for (int hb = 0; hb < 4; ++hb) {
      op[(4 * g + jj) * 64 + hb * 16 + l16] = __float2half(o0[hb][jj] / l0r);
      op[(16 + 4 * g + jj) * 64 + hb * 16 + l16] = __float2half(o1[hb][jj] / l1r);
    }
  }
  float* ml = ML + u * 256 + w * 64;
  if (lane < 16) {
    ml[lane] = m0;
    ml[32 + lane] = l0;
  } else if (lane < 32) {
    ml[lane] = m1;
    ml[32 + lane] = l1;
  }
}

// ---------------- combine partials: one wave per output row ----------------
template <int PT, int NU_B>
__global__ __launch_bounds__(256) void attn_combine_kernel(
    const __half* __restrict__ OP, const float* __restrict__ ML,
    float* __restrict__ out) {
  const int tid = threadIdx.x;
  const int w = tid >> 6;
  const int lane = tid & 63;
  const int rid = blockIdx.x * 4 + w;        // [0, 16384)
  const int b = rid >> 12;
  const int rr = rid & 4095;
  const int j4 = rr >> 7;                    // qblock [0,32)
  const int local = rr & 127;
  const int nparts = (2 * j4 + 2 + PT - 1) / PT;
  int prefix = 0;
  for (int k = 0; k < j4; ++k) prefix += (2 * k + 2 + PT - 1) / PT;
  const size_t base = (size_t)b * NU_B + prefix;
  const int wv = local >> 5;
  const int tile = (local >> 4) & 1;
  const int rowin = local & 15;
  const int mi = wv * 64 + tile * 16 + rowin;

  float M = -1e30f;
  for (int p = 0; p < nparts; ++p) M = fmaxf(M, ML[(base + p) * 256 + mi]);
  float wsum = 0.f, acc = 0.f;
  for (int p = 0; p < nparts; ++p) {
    const float m = ML[(base + p) * 256 + mi];
    const float l = ML[(base + p) * 256 + 32 + mi];
    const float wg = l * __expf(m - M);
    wsum += wg;
    acc += wg * __half2float(OP[(base + p) * 8192 + (size_t)local * 64 + lane]);
  }
  out[(size_t)rid * 64 + lane] = acc / wsum;
}

extern "C" void kernel_launch(void* const* d_in, const int* in_sizes, int n_in,
                              void* d_out, int out_size, void* d_ws, size_t ws_size,
                              hipStream_t stream) {
  const float* x  = (const float*)d_in[0];
  const float* Wq = (const float*)d_in[1];
  const float* Wk = (const float*)d_in[2];
  const float* Wv = (const float*)d_in[3];
  float* out = (float*)d_out;

  const size_t N = (size_t)4 * 4096 * 64;   // elements per q/k/v array
  const size_t WN = (size_t)192 * 1024;     // W frag-stream elements
  unsigned short* qh = (unsigned short*)d_ws;
  unsigned short* ql = qh + N;
  unsigned short* kh = ql + N;
  unsigned short* kl = kh + N;
  unsigned short* vt = kl + N;              // [B][64][T] transposed V
  unsigned short* Wth = vt + N;
  unsigned short* Wtl = Wth + WN;
  __half* OP = (__half*)(Wtl + WN);
  const size_t base_need = (5 * N + 2 * WN) * 2;

  const size_t NU4 = 4 * 272, NU8 = 4 * 144;
  const size_t need4 = base_need + NU4 * 8192 * 2 + NU4 * 256 * 4;   // ~41 MB
  const size_t need8 = base_need + NU8 * 8192 * 2 + NU8 * 256 * 4;   // ~32 MB

  wsplit_kernel<<<dim3(96), dim3(256), 0, stream>>>(Wq, Wk, Wv, Wth, Wtl);
  proj_mfma_kernel<<<dim3(768), dim3(256), 0, stream>>>(x, Wth, Wtl, qh, ql, kh, kl, vt);
  if (ws_size >= need4) {
    float* ML = (float*)(OP + NU4 * 8192);
    attn_part_block_kernel<4, 272><<<dim3(NU4), dim3(256), 0, stream>>>(qh, ql, kh, kl, vt, OP, ML);
    attn_combine_kernel<4, 272><<<dim3(4096), dim3(256), 0, stream>>>(OP, ML, out);
  } else {
    float* ML = (float*)(OP + NU8 * 8192);
    attn_part_block_kernel<8, 144><<<dim3(NU8), dim3(256), 0, stream>>>(qh, ql, kh, kl, vt, OP, ML);
    attn_combine_kernel<8, 144><<<dim3(4096), dim3(256), 0, stream>>>(OP, ML, out);
  }
}

// Round 18
// 90.607 us; speedup vs baseline: 1.0343x; 1.0343x over previous
//
#include <hip/hip_runtime.h>
#include <hip/hip_fp16.h>

// B=4, T=4096, C=1024, H=64 single attention head, causal, NO 1/sqrt(d) scale.
// wsplit: W -> hi/lo bf16 frag-stream. proj_mfma: 3-term split-bf16 MFMA GEMM ->
// qh/ql/kh/kl (hi/lo bf16) + vt (bf16 [B][64][T]); 64 rows/block, W reg-dbuf,
// x 2-step reg prefetch, cvt_pk split conversion.
// attn_part_block: 128 q-rows/block, K/V double-buffered LDS (2-phase pipeline),
// swapped QK^T, V-hoist, defer-max. PT=4 parts. combine: one wave per output row.
// [ROUND 18: reversion to best-known configuration (rounds 13/16, 90.9/91.1 us)]

typedef __attribute__((ext_vector_type(8))) short bf16x8;
typedef __attribute__((ext_vector_type(8))) unsigned short u16x8;
typedef __attribute__((ext_vector_type(4))) float f32x4;

__device__ __forceinline__ unsigned short f2bf(float f) {
  unsigned u = __float_as_uint(f);
  u += 0x7fffu + ((u >> 16) & 1u);   // RTNE (finite values only here)
  return (unsigned short)(u >> 16);
}
__device__ __forceinline__ float bf2f(unsigned short s) {
  return __uint_as_float(((unsigned)s) << 16);
}
__device__ __forceinline__ unsigned cvt_pk_bf16(float lo, float hi) {
  unsigned r;
  asm("v_cvt_pk_bf16_f32 %0, %1, %2" : "=v"(r) : "v"(lo), "v"(hi));
  return r;
}
__device__ __forceinline__ void gload_lds16(const void* g, void* l) {
  __builtin_amdgcn_global_load_lds(
      (const __attribute__((address_space(1))) unsigned int*)g,
      (__attribute__((address_space(3))) unsigned int*)l, 16, 0, 0);
}
// XOR swizzle within a [64][128B] LDS tile: spreads column-strided b128 reads
#define KSWZ(row, colb) ((((row) * 128) + (colb)) ^ (((row) & 7) << 4))

// ---------------- W split: frag-stream layout ----------------
__global__ __launch_bounds__(256) void wsplit_kernel(
    const float* __restrict__ Wq, const float* __restrict__ Wk,
    const float* __restrict__ Wv,
    unsigned short* __restrict__ Wth, unsigned short* __restrict__ Wtl) {
  const int fl = blockIdx.x * 256 + threadIdx.x;   // [0, 24576)
  const int lane = fl & 63;
  const int rest = fl >> 6;        // [0, 384)
  const int nf = rest % 12;
  const int ksq = rest / 12;       // [0, 32)
  const int n = nf * 16 + (lane & 15);
  const int k0 = ksq * 32 + (lane >> 4) * 8;
  const float* wp = (n < 64) ? Wq : ((n < 128) ? Wk : Wv);
  const int h = n & 63;
  u16x8 hi, lo;
#pragma unroll
  for (int j = 0; j < 8; ++j) {
    float v = wp[(size_t)(k0 + j) * 64 + h];
    unsigned short hh = f2bf(v);
    hi[j] = hh;
    lo[j] = f2bf(v - bf2f(hh));
  }
  const size_t base = (size_t)fl * 8;
  *reinterpret_cast<u16x8*>(&Wth[base]) = hi;
  *reinterpret_cast<u16x8*>(&Wtl[base]) = lo;
}

// convert 8 f32 (two float4) -> hi/lo bf16x8 and store to LDS (16B each)
__device__ __forceinline__ void cvt_store8(unsigned short* dh, unsigned short* dl,
                                           const float4& a, const float4& b) {
  float v[8] = {a.x, a.y, a.z, a.w, b.x, b.y, b.z, b.w};
  uint4 hp, lp;
  unsigned* hpp = reinterpret_cast<unsigned*>(&hp);
  unsigned* lpp = reinterpret_cast<unsigned*>(&lp);
#pragma unroll
  for (int p = 0; p < 4; ++p) {
    const unsigned h = cvt_pk_bf16(v[2 * p], v[2 * p + 1]);
    hpp[p] = h;
    const float h0 = __uint_as_float(h << 16);
    const float h1 = __uint_as_float(h & 0xffff0000u);
    lpp[p] = cvt_pk_bf16(v[2 * p] - h0, v[2 * p + 1] - h1);
  }
  *reinterpret_cast<uint4*>(dh) = hp;
  *reinterpret_cast<uint4*>(dl) = lp;
}

// ---------------- projection via MFMA: [16384 x 1024] * [1024 x 192] ----------------
// 256 blocks x 64 rows, 4 waves (wave = 48 cols, 4 mfrags). W double-buffered in
// regs, x 2-step reg prefetch, LDS A-tile double-buffered.
__global__ __launch_bounds__(256) void proj_mfma_kernel(
    const float* __restrict__ x,
    const unsigned short* __restrict__ Wth, const unsigned short* __restrict__ Wtl,
    unsigned short* __restrict__ qh, unsigned short* __restrict__ ql,
    unsigned short* __restrict__ kh, unsigned short* __restrict__ kl,
    unsigned short* __restrict__ vt) {
  __shared__ unsigned short Ah[2][64][72];
  __shared__ unsigned short Al[2][64][72];
  const int tid = threadIdx.x;
  const int w = tid >> 6;
  const int lane = tid & 63;
  const int l16 = lane & 15;
  const int g = lane >> 4;
  const int row0 = blockIdx.x * 64;
  const int sr = tid >> 2;          // staging row 0..63
  const int sc = (tid & 3) * 16;    // staging col 0,16,32,48

  f32x4 acc[4][3];
#pragma unroll
  for (int m = 0; m < 4; ++m)
#pragma unroll
    for (int f = 0; f < 3; ++f) {
      f32x4 z = {0.f, 0.f, 0.f, 0.f};
      acc[m][f] = z;
    }

  const float* xp = &x[(size_t)(row0 + sr) * 1024 + sc];

  // x register sets: set0 = even slices, set1 = odd slices (4 float4 = 16 floats)
  float4 xs0[4], xs1[4];
#pragma unroll
  for (int i = 0; i < 4; ++i) xs0[i] = *reinterpret_cast<const float4*>(xp + i * 4);
#pragma unroll
  for (int i = 0; i < 4; ++i) xs1[i] = *reinterpret_cast<const float4*>(xp + 64 + i * 4);
  cvt_store8(&Ah[0][sr][sc], &Al[0][sr][sc], xs0[0], xs0[1]);       // slice 0 -> buf 0
  cvt_store8(&Ah[0][sr][sc + 8], &Al[0][sr][sc + 8], xs0[2], xs0[3]);

  // W current registers (step 0)
  bf16x8 bhc[2][3], blc[2][3];
#pragma unroll
  for (int ks = 0; ks < 2; ++ks)
#pragma unroll
    for (int f = 0; f < 3; ++f) {
      const size_t off = ((size_t)ks * 12 + (w * 3 + f)) * 512 + lane * 8;
      bhc[ks][f] = *reinterpret_cast<const bf16x8*>(&Wth[off]);
      blc[ks][f] = *reinterpret_cast<const bf16x8*>(&Wtl[off]);
    }

#pragma unroll 2
  for (int step = 0; step < 16; ++step) {
    __syncthreads();
    // prefetch W for step+1
    bf16x8 bhn[2][3], bln[2][3];
    if (step < 15) {
#pragma unroll
      for (int ks = 0; ks < 2; ++ks)
#pragma unroll
        for (int f = 0; f < 3; ++f) {
          const size_t off =
              ((size_t)((step + 1) * 2 + ks) * 12 + (w * 3 + f)) * 512 + lane * 8;
          bhn[ks][f] = *reinterpret_cast<const bf16x8*>(&Wth[off]);
          bln[ks][f] = *reinterpret_cast<const bf16x8*>(&Wtl[off]);
        }
    }
    // issue x loads for slice step+2 into set[step&1]
    if (step < 14) {
      const float* px = xp + (size_t)(step + 2) * 64;
      if ((step & 1) == 0) {
#pragma unroll
        for (int i = 0; i < 4; ++i) xs0[i] = *reinterpret_cast<const float4*>(px + i * 4);
      } else {
#pragma unroll
        for (int i = 0; i < 4; ++i) xs1[i] = *reinterpret_cast<const float4*>(px + i * 4);
      }
    }
    // MFMAs on buf[step&1] with current W regs
    const int cur = step & 1;
#pragma unroll
    for (int ks = 0; ks < 2; ++ks) {
      bf16x8 ah[4], al[4];
#pragma unroll
      for (int m = 0; m < 4; ++m) {
        const int ro = m * 16 + l16;
        const int co = ks * 32 + g * 8;
        ah[m] = *reinterpret_cast<const bf16x8*>(&Ah[cur][ro][co]);
        al[m] = *reinterpret_cast<const bf16x8*>(&Al[cur][ro][co]);
      }
#pragma unroll
      for (int m = 0; m < 4; ++m)
#pragma unroll
        for (int f = 0; f < 3; ++f) {
          acc[m][f] = __builtin_amdgcn_mfma_f32_16x16x32_bf16(ah[m], bhc[ks][f], acc[m][f], 0, 0, 0);
          acc[m][f] = __builtin_amdgcn_mfma_f32_16x16x32_bf16(ah[m], blc[ks][f], acc[m][f], 0, 0, 0);
          acc[m][f] = __builtin_amdgcn_mfma_f32_16x16x32_bf16(al[m], bhc[ks][f], acc[m][f], 0, 0, 0);
        }
    }
    // convert slice step+1 (loaded >= 1 full step ago) -> buf[cur^1]
    if (step < 15) {
      if (((step + 1) & 1) == 0) {
        cvt_store8(&Ah[cur ^ 1][sr][sc], &Al[cur ^ 1][sr][sc], xs0[0], xs0[1]);
        cvt_store8(&Ah[cur ^ 1][sr][sc + 8], &Al[cur ^ 1][sr][sc + 8], xs0[2], xs0[3]);
      } else {
        cvt_store8(&Ah[cur ^ 1][sr][sc], &Al[cur ^ 1][sr][sc], xs1[0], xs1[1]);
        cvt_store8(&Ah[cur ^ 1][sr][sc + 8], &Al[cur ^ 1][sr][sc + 8], xs1[2], xs1[3]);
      }
    }
    // rotate W registers
#pragma unroll
    for (int ks = 0; ks < 2; ++ks)
#pragma unroll
      for (int f = 0; f < 3; ++f) {
        bhc[ks][f] = bhn[ks][f];
        blc[ks][f] = bln[ks][f];
      }
  }

  const int b = row0 >> 12;
  const int tbase = row0 & 4095;
#pragma unroll
  for (int m = 0; m < 4; ++m)
#pragma unroll
    for (int f = 0; f < 3; ++f) {
      const int nn = w * 48 + f * 16;
      if (nn < 64) {
        const int h = nn + l16;
#pragma unroll
        for (int j = 0; j < 4; ++j) {
          const int row = row0 + m * 16 + 4 * g + j;
          const float val = acc[m][f][j];
          const unsigned short hi = f2bf(val);
          qh[(size_t)row * 64 + h] = hi;
          ql[(size_t)row * 64 + h] = f2bf(val - bf2f(hi));
        }
      } else if (nn < 128) {
        const int h = nn - 64 + l16;
#pragma unroll
        for (int j = 0; j < 4; ++j) {
          const int row = row0 + m * 16 + 4 * g + j;
          const float val = acc[m][f][j];
          const unsigned short hi = f2bf(val);
          kh[(size_t)row * 64 + h] = hi;
          kl[(size_t)row * 64 + h] = f2bf(val - bf2f(hi));
        }
      } else {
        const int h = nn - 128 + l16;
        ushort4 pv;
        pv.x = f2bf(acc[m][f][0]);
        pv.y = f2bf(acc[m][f][1]);
        pv.z = f2bf(acc[m][f][2]);
        pv.w = f2bf(acc[m][f][3]);
        const size_t a = ((size_t)b * 64 + h) * 4096 + tbase + m * 16 + 4 * g;
        *reinterpret_cast<ushort4*>(&vt[a]) = pv;
      }
    }
}

// ---------------- attention partials: 128-row block, double-buffered LDS K/V ----------------
// 2-phase pipeline: top-of-loop barrier drains buf[cur]; stage(t+1 -> cur^1)
// issued immediately after, in flight during compute(t).
template <int PT, int NU_B>
__global__ __launch_bounds__(256) void attn_part_block_kernel(
    const unsigned short* __restrict__ qh, const unsigned short* __restrict__ ql,
    const unsigned short* __restrict__ kh, const unsigned short* __restrict__ kl,
    const unsigned short* __restrict__ vt,
    __half* __restrict__ OP, float* __restrict__ ML) {
  __shared__ __align__(16) unsigned short Khs[2][4096];  // [64][64] bf16, XOR-swizzled
  __shared__ __align__(16) unsigned short Kls[2][4096];
  __shared__ __align__(16) unsigned short Vs[2][4096];   // rows = h, cols = kv
  __shared__ __align__(16) unsigned short pbuf[4][2][16][88];
  const int tid = threadIdx.x;
  const int w = tid >> 6;
  const int lane = tid & 63;
  const int l16 = lane & 15;
  const int g = lane >> 4;

  const int bx = blockIdx.x;
  const int xc = bx & 7;
  const int b = xc >> 1;                       // batch -> 2 XCDs
  const int s = 2 * (bx >> 3) + (xc & 1);      // [0, NU_B)
  int k = 0, pref = 0;
  for (;;) {
    const int np = (2 * k + 2 + PT - 1) / PT;
    if (s < pref + np) break;
    pref += np;
    ++k;
  }
  const int j4 = k;
  const int p = s - pref;
  const int ntiles = 2 * j4 + 2;
  const int t0 = p * PT;
  const int t1 = min(ntiles, t0 + PT);
  const int q0 = j4 * 128 + w * 32;            // wave's q base
  const size_t rowbase = (size_t)b * 4096;

  // staging indices (per thread, loop-invariant)
  const int te0 = w * 64 + lane;               // half 0 chunk
  const int te1 = 256 + w * 64 + lane;         // half 1 chunk
  const int r0_ = te0 >> 3, c80 = (te0 & 7) ^ (r0_ & 7);
  const int r1_ = te1 >> 3, c81 = (te1 & 7) ^ (r1_ & 7);
  const int lo0 = te0 * 16, lo1 = te1 * 16;    // linear LDS byte offsets

  bf16x8 q0hf[2], q0lf[2], q1hf[2], q1lf[2];
#pragma unroll
  for (int ss = 0; ss < 2; ++ss) {
    size_t a0 = (rowbase + q0 + l16) * 64 + ss * 32 + g * 8;
    q0hf[ss] = *reinterpret_cast<const bf16x8*>(&qh[a0]);
    q0lf[ss] = *reinterpret_cast<const bf16x8*>(&ql[a0]);
    size_t a1 = a0 + 16 * 64;
    q1hf[ss] = *reinterpret_cast<const bf16x8*>(&qh[a1]);
    q1lf[ss] = *reinterpret_cast<const bf16x8*>(&ql[a1]);
  }

  f32x4 o0[4], o1[4];
#pragma unroll
  for (int hb = 0; hb < 4; ++hb) {
    f32x4 z = {0.f, 0.f, 0.f, 0.f};
    o0[hb] = z;
    o1[hb] = z;
  }
  float m0 = -1e30f, l0 = 0.f, m1 = -1e30f, l1 = 0.f;

  // prologue: stage tile t0 into buf 0
  {
    const int kv0 = t0 * 64;
    gload_lds16(&kh[(rowbase + kv0 + r0_) * 64 + c80 * 8], (char*)Khs[0] + lo0);
    gload_lds16(&kl[(rowbase + kv0 + r0_) * 64 + c80 * 8], (char*)Kls[0] + lo0);
    gload_lds16(&vt[((size_t)b * 64 + r0_) * 4096 + kv0 + c80 * 8], (char*)Vs[0] + lo0);
    gload_lds16(&kh[(rowbase + kv0 + r1_) * 64 + c81 * 8], (char*)Khs[0] + lo1);
    gload_lds16(&kl[(rowbase + kv0 + r1_) * 64 + c81 * 8], (char*)Kls[0] + lo1);
    gload_lds16(&vt[((size_t)b * 64 + r1_) * 4096 + kv0 + c81 * 8], (char*)Vs[0] + lo1);
  }

  int cur = 0;
  for (int t = t0; t < t1; ++t) {
    __syncthreads();   // drains vmcnt: buf[cur] ready for all waves
    // prefetch next tile into buf[cur^1] (in flight during compute)
    if (t + 1 < t1) {
      const int kn = (t + 1) * 64;
      gload_lds16(&kh[(rowbase + kn + r0_) * 64 + c80 * 8], (char*)Khs[cur ^ 1] + lo0);
      gload_lds16(&kl[(rowbase + kn + r0_) * 64 + c80 * 8], (char*)Kls[cur ^ 1] + lo0);
      gload_lds16(&vt[((size_t)b * 64 + r0_) * 4096 + kn + c80 * 8], (char*)Vs[cur ^ 1] + lo0);
      gload_lds16(&kh[(rowbase + kn + r1_) * 64 + c81 * 8], (char*)Khs[cur ^ 1] + lo1);
      gload_lds16(&kl[(rowbase + kn + r1_) * 64 + c81 * 8], (char*)Kls[cur ^ 1] + lo1);
      gload_lds16(&vt[((size_t)b * 64 + r1_) * 4096 + kn + c81 * 8], (char*)Vs[cur ^ 1] + lo1);
    }
    const int kv0 = t * 64;

    f32x4 s0[4], s1[4];
#pragma unroll
    for (int kb = 0; kb < 4; ++kb) {
      bf16x8 khf[2], klf[2];
#pragma unroll
      for (int ss = 0; ss < 2; ++ss) {
        const int row = kb * 16 + l16;
        const int colb = ss * 64 + g * 16;
        khf[ss] = *reinterpret_cast<const bf16x8*>((const char*)Khs[cur] + KSWZ(row, colb));
        klf[ss] = *reinterpret_cast<const bf16x8*>((const char*)Kls[cur] + KSWZ(row, colb));
      }
      f32x4 a0 = {0.f, 0.f, 0.f, 0.f};
      f32x4 a1 = {0.f, 0.f, 0.f, 0.f};
#pragma unroll
      for (int ss = 0; ss < 2; ++ss) {
        a0 = __builtin_amdgcn_mfma_f32_16x16x32_bf16(khf[ss], q0hf[ss], a0, 0, 0, 0);
        a0 = __builtin_amdgcn_mfma_f32_16x16x32_bf16(khf[ss], q0lf[ss], a0, 0, 0, 0);
        a0 = __builtin_amdgcn_mfma_f32_16x16x32_bf16(klf[ss], q0hf[ss], a0, 0, 0, 0);
        a1 = __builtin_amdgcn_mfma_f32_16x16x32_bf16(khf[ss], q1hf[ss], a1, 0, 0, 0);
        a1 = __builtin_amdgcn_mfma_f32_16x16x32_bf16(khf[ss], q1lf[ss], a1, 0, 0, 0);
        a1 = __builtin_amdgcn_mfma_f32_16x16x32_bf16(klf[ss], q1hf[ss], a1, 0, 0, 0);
      }
      s0[kb] = a0;
      s1[kb] = a1;
    }
    // V fragments from LDS, issued EARLY (complete under softmax)
    bf16x8 vf[2][4];
#pragma unroll
    for (int ks = 0; ks < 2; ++ks)
#pragma unroll
      for (int hb = 0; hb < 4; ++hb) {
        const int row = hb * 16 + l16;
        const int colb = ks * 64 + g * 16;
        vf[ks][hb] = *reinterpret_cast<const bf16x8*>((const char*)Vs[cur] + KSWZ(row, colb));
      }
    if (kv0 + 63 > q0) {
#pragma unroll
      for (int kb = 0; kb < 4; ++kb)
#pragma unroll
        for (int jj = 0; jj < 4; ++jj) {
          const int kvg = kv0 + kb * 16 + 4 * g + jj;
          if (kvg > q0 + l16) s0[kb][jj] = -1e30f;
          if (kvg > q0 + 16 + l16) s1[kb][jj] = -1e30f;
        }
    }
    float rm0 = s0[0][0], rm1 = s1[0][0];
#pragma unroll
    for (int kb = 0; kb < 4; ++kb) {
      float c0 = fmaxf(fmaxf(s0[kb][0], s0[kb][1]), fmaxf(s0[kb][2], s0[kb][3]));
      float c1 = fmaxf(fmaxf(s1[kb][0], s1[kb][1]), fmaxf(s1[kb][2], s1[kb][3]));
      rm0 = fmaxf(rm0, c0);
      rm1 = fmaxf(rm1, c1);
    }
    rm0 = fmaxf(rm0, __shfl_xor(rm0, 16));
    rm0 = fmaxf(rm0, __shfl_xor(rm0, 32));
    rm1 = fmaxf(rm1, __shfl_xor(rm1, 16));
    rm1 = fmaxf(rm1, __shfl_xor(rm1, 32));
    const bool r0 = !__all(rm0 - m0 <= 8.f);   // wave-uniform
    const bool r1 = !__all(rm1 - m1 <= 8.f);
    const float mu0 = r0 ? fmaxf(m0, rm0) : m0;
    const float mu1 = r1 ? fmaxf(m1, rm1) : m1;
    const float al0 = r0 ? __expf(m0 - mu0) : 1.f;
    const float al1 = r1 ? __expf(m1 - mu1) : 1.f;
    float ps0 = 0.f, ps1 = 0.f;
#pragma unroll
    for (int kb = 0; kb < 4; ++kb)
#pragma unroll
      for (int jj = 0; jj < 4; ++jj) {
        const float e0 = __expf(s0[kb][jj] - mu0);
        const float e1 = __expf(s1[kb][jj] - mu1);
        s0[kb][jj] = e0;
        s1[kb][jj] = e1;
        ps0 += e0;
        ps1 += e1;
      }
    ps0 += __shfl_xor(ps0, 16);
    ps0 += __shfl_xor(ps0, 32);
    ps1 += __shfl_xor(ps1, 16);
    ps1 += __shfl_xor(ps1, 32);
    l0 = l0 * al0 + ps0;
    m0 = mu0;
    l1 = l1 * al1 + ps1;
    m1 = mu1;
#pragma unroll
    for (int kb = 0; kb < 4; ++kb) {
      *reinterpret_cast<unsigned*>(&pbuf[w][0][l16][kb * 16 + 4 * g]) =
          cvt_pk_bf16(s0[kb][0], s0[kb][1]);
      *reinterpret_cast<unsigned*>(&pbuf[w][0][l16][kb * 16 + 4 * g + 2]) =
          cvt_pk_bf16(s0[kb][2], s0[kb][3]);
      *reinterpret_cast<unsigned*>(&pbuf[w][1][l16][kb * 16 + 4 * g]) =
          cvt_pk_bf16(s1[kb][0], s1[kb][1]);
      *reinterpret_cast<unsigned*>(&pbuf[w][1][l16][kb * 16 + 4 * g + 2]) =
          cvt_pk_bf16(s1[kb][2], s1[kb][3]);
    }
    if (r0) {
#pragma unroll
      for (int jj = 0; jj < 4; ++jj) {
        const float a0r = __shfl(al0, 4 * g + jj);
#pragma unroll
        for (int hb = 0; hb < 4; ++hb) o0[hb][jj] *= a0r;
      }
    }
    if (r1) {
#pragma unroll
      for (int jj = 0; jj < 4; ++jj) {
        const float a1r = __shfl(al1, 4 * g + jj);
#pragma unroll
        for (int hb = 0; hb < 4; ++hb) o1[hb][jj] *= a1r;
      }
    }
    asm volatile("s_waitcnt lgkmcnt(0)" ::: "memory");
#pragma unroll
    for (int ks = 0; ks < 2; ++ks) {
      bf16x8 pa0 = *reinterpret_cast<const bf16x8*>(&pbuf[w][0][l16][ks * 32 + g * 8]);
      bf16x8 pa1 = *reinterpret_cast<const bf16x8*>(&pbuf[w][1][l16][ks * 32 + g * 8]);
#pragma unroll
      for (int hb = 0; hb < 4; ++hb) {
        o0[hb] = __builtin_amdgcn_mfma_f32_16x16x32_bf16(pa0, vf[ks][hb], o0[hb], 0, 0, 0);
        o1[hb] = __builtin_amdgcn_mfma_f32_16x16x32_bf16(pa1, vf[ks][hb], o1[hb], 0, 0, 0);
      }
    }
    cur ^= 1;
  }

  const size_t u = (size_t)b * NU_B + s;
  __half* op = OP + u * 8192 + (size_t)w * 32 * 64;   // [128][64] per unit
#pragma unroll
  for (int jj = 0; jj < 4; ++jj) {
    const int srcr = 4 * g + jj;
    const float l0r = __shfl(l0, srcr);
    const float l1r = __shfl(l1, srcr);
#pragma unroll
    for (int hb = 0; hb < 4; ++hb) {
      op[(4 * g + jj) * 64 + hb * 16 + l16] = __float2half(o0[hb][jj] / l0r);
      op[(16 + 4 * g + jj) * 64 + hb * 16 + l16] = __float2half(o1[hb][jj] / l1r);
    }
  }
  float* ml = ML + u * 256 + w * 64;
  if (lane < 16) {
    ml[lane] = m0;
    ml[32 + lane] = l0;
  } else if (lane < 32) {
    ml[lane] = m1;
    ml[32 + lane] = l1;
  }
}

// ---------------- combine partials: one wave per output row ----------------
template <int PT, int NU_B>
__global__ __launch_bounds__(256) void attn_combine_kernel(
    const __half* __restrict__ OP, const float* __restrict__ ML,
    float* __restrict__ out) {
  const int tid = threadIdx.x;
  const int w = tid >> 6;
  const int lane = tid & 63;
  const int rid = blockIdx.x * 4 + w;        // [0, 16384)
  const int b = rid >> 12;
  const int rr = rid & 4095;
  const int j4 = rr >> 7;                    // qblock [0,32)
  const int local = rr & 127;
  const int nparts = (2 * j4 + 2 + PT - 1) / PT;
  int prefix = 0;
  for (int k = 0; k < j4; ++k) prefix += (2 * k + 2 + PT - 1) / PT;
  const size_t base = (size_t)b * NU_B + prefix;
  const int wv = local >> 5;
  const int tile = (local >> 4) & 1;
  const int rowin = local & 15;
  const int mi = wv * 64 + tile * 16 + rowin;

  float M = -1e30f;
  for (int p = 0; p < nparts; ++p) M = fmaxf(M, ML[(base + p) * 256 + mi]);
  float wsum = 0.f, acc = 0.f;
  for (int p = 0; p < nparts; ++p) {
    const float m = ML[(base + p) * 256 + mi];
    const float l = ML[(base + p) * 256 + 32 + mi];
    const float wg = l * __expf(m - M);
    wsum += wg;
    acc += wg * __half2float(OP[(base + p) * 8192 + (size_t)local * 64 + lane]);
  }
  out[(size_t)rid * 64 + lane] = acc / wsum;
}

extern "C" void kernel_launch(void* const* d_in, const int* in_sizes, int n_in,
                              void* d_out, int out_size, void* d_ws, size_t ws_size,
                              hipStream_t stream) {
  const float* x  = (const float*)d_in[0];
  const float* Wq = (const float*)d_in[1];
  const float* Wk = (const float*)d_in[2];
  const float* Wv = (const float*)d_in[3];
  float* out = (float*)d_out;

  const size_t N = (size_t)4 * 4096 * 64;   // elements per q/k/v array
  const size_t WN = (size_t)192 * 1024;     // W frag-stream elements
  unsigned short* qh = (unsigned short*)d_ws;
  unsigned short* ql = qh + N;
  unsigned short* kh = ql + N;
  unsigned short* kl = kh + N;
  unsigned short* vt = kl + N;              // [B][64][T] transposed V
  unsigned short* Wth = vt + N;
  unsigned short* Wtl = Wth + WN;
  __half* OP = (__half*)(Wtl + WN);
  const size_t base_need = (5 * N + 2 * WN) * 2;

  const size_t NU4 = 4 * 272, NU8 = 4 * 144;
  const size_t need4 = base_need + NU4 * 8192 * 2 + NU4 * 256 * 4;   // ~41 MB
  const size_t need8 = base_need + NU8 * 8192 * 2 + NU8 * 256 * 4;   // ~32 MB

  wsplit_kernel<<<dim3(96), dim3(256), 0, stream>>>(Wq, Wk, Wv, Wth, Wtl);
  proj_mfma_kernel<<<dim3(256), dim3(256), 0, stream>>>(x, Wth, Wtl, qh, ql, kh, kl, vt);
  if (ws_size >= need4) {
    float* ML = (float*)(OP + NU4 * 8192);
    attn_part_block_kernel<4, 272><<<dim3(NU4), dim3(256), 0, stream>>>(qh, ql, kh, kl, vt, OP, ML);
    attn_combine_kernel<4, 272><<<dim3(4096), dim3(256), 0, stream>>>(OP, ML, out);
  } else {
    float* ML = (float*)(OP + NU8 * 8192);
    attn_part_block_kernel<8, 144><<<dim3(NU8), dim3(256), 0, stream>>>(qh, ql, kh, kl, vt, OP, ML);
    attn_combine_kernel<8, 144><<<dim3(4096), dim3(256), 0, stream>>>(OP, ML, out);
  }
}